// Round 13
// baseline (352.190 us; speedup 1.0000x reference)
//
#include <hip/hip_runtime.h>
#include <hip/hip_bf16.h>

typedef unsigned int u32;
typedef unsigned short u16;
typedef __attribute__((ext_vector_type(8))) short short8;   // 8 bf16 (4 VGPRs) MFMA A/B frag
typedef __attribute__((ext_vector_type(4))) float f32x4;    // MFMA C/D frag
typedef __attribute__((ext_vector_type(4))) u32 u32x4;
typedef __attribute__((ext_vector_type(2))) u32 u32x2;

#define DD 32
#define EE 8
#define HH 64
#define TT 10
#define BATCH 16384
#define EPB 64          // batch elements per block (grid 256 = 1 block/CU)
#define DYN_LDS 88064   // bytes: xdb 5120 + fsb 33792 + lg 3072 + usb 9216 + scratch 36864

#if __has_builtin(__builtin_amdgcn_exp2f)
#define EXP2F(x) __builtin_amdgcn_exp2f(x)
#else
#define EXP2F(x) __builtin_exp2f(x)
#endif

__device__ __forceinline__ float fast_tanh(float x) {
  float e = EXP2F(x * 2.885390082f);
  return 1.f - 2.f * __builtin_amdgcn_rcpf(e + 1.f);
}
__device__ __forceinline__ u16 f2b_rn(float v) {
  return (u16)((__float_as_uint(v) + 0x8000u) >> 16);
}
__device__ __forceinline__ u32 pack2_rn(float a, float b) {
  return __builtin_amdgcn_perm(__float_as_uint(b) + 0x8000u,
                               __float_as_uint(a) + 0x8000u, 0x07060302u);
}
__device__ __forceinline__ float unp_lo(u32 p) { return __uint_as_float(p << 16); }
__device__ __forceinline__ float unp_hi(u32 p) { return __uint_as_float(p & 0xffff0000u); }
__device__ __forceinline__ short8 lds_frag(const u32* p) {
  u32x4 v = *(const u32x4*)p;               // ds_read_b128 (16B-aligned by construction)
  return __builtin_bit_cast(short8, v);
}
__device__ __forceinline__ f32x4 bcast4(float v) { f32x4 c; c[0]=v; c[1]=v; c[2]=v; c[3]=v; return c; }

// wave = expert (8 waves, 512 thr), 64 elems/block, grid 256. R12 base (276 us).
// CHANGE vs R12: fsb (the f matrix) is XOR-SWIZZLED at 16B-block granularity
// (block ^= row&7) on all three access sites (phase-A write, G1 A-frag read,
// phase-C read). R12's plain stride-132 rows put phase C's per-lane b64 reads
// into 8-way bank aliasing (row stride ≡ 4 mod 32); R8's swizzled layout
// measured 36% fewer SQ_LDS_BANK_CONFLICT. Also: softmax without
// max-subtraction (logits bounded; R8-validated, absmax identical).
// REGISTER LAW (R5-R12): waves/SIMD = floor(256/VGPR); 1 block of 8 waves/CU
// pins us at 2 waves/SIMD; weights-resident needs VGPR in [100,128]; any
// launch-bounds cap <=128 dumps the frags (FETCH 2 MB -> GBs, 2.5-5x slower).
__global__ __launch_bounds__(512) void ame_ode_kernel(
    const float* __restrict__ x0, const float* __restrict__ tspan,
    const float* __restrict__ W1, const float* __restrict__ b1,
    const float* __restrict__ W2, const float* __restrict__ b2,
    const float* __restrict__ W3, const float* __restrict__ b3,
    const float* __restrict__ Gw1, const float* __restrict__ Gb1,
    const float* __restrict__ Gw2, const float* __restrict__ Gb2,
    float* __restrict__ out)
{
  extern __shared__ __align__(16) u32 dynbuf[];
  u32*  const xdb = dynbuf;                    // [EPB][20] u32: xs bf16x2 (5120 B)
  u32*  const fsb = dynbuf + 1280;             // [EPB][132] u32: f bf16x2, XOR-swizzled 16B blocks (33792 B)
  float* const lg = (float*)(dynbuf + 9728);   // [EPB][12]: logits (3072 B)
  u32*  const usb = dynbuf + 10496;            // [EPB][36] u32: gating U (9216 B)
  u32*  const hs  = dynbuf + 12800;            // [8 waves][2 regions][16][36] u32 scratch (36864 B)

  const int tid  = threadIdx.x;
  const int lane = tid & 63;
  const int l15  = lane & 15;
  const int quad = lane >> 4;
  const int e    = __builtin_amdgcn_readfirstlane(tid >> 6);   // wave-uniform expert id
  const int b    = blockIdx.x * EPB + lane;                    // this lane's batch element

  const float* W1f = W1 + e * (DD + 1) * HH;
  const float* b1f = b1 + e * HH;
  const float* W2f = W2 + e * HH * HH;
  const float* b2f = b2 + e * HH;
  const float* W3f = W3 + e * HH * DD;
  const float* b3f = b3 + e * DD;

  // ---- expert-weight B-frags: B[k=quad*8+j][n=l15(+16nt)] ----
  short8 bw1[4], bw2[2][4], bw3[2][2];
  #pragma unroll
  for (int nt = 0; nt < 4; nt++)
    #pragma unroll
    for (int j = 0; j < 8; j++)
      bw1[nt][j] = (short)f2b_rn(W1f[(quad * 8 + j) * HH + nt * 16 + l15]);
  #pragma unroll
  for (int ks = 0; ks < 2; ks++)
    #pragma unroll
    for (int nt = 0; nt < 4; nt++)
      #pragma unroll
      for (int j = 0; j < 8; j++)
        bw2[ks][nt][j] = (short)f2b_rn(W2f[(ks * 32 + quad * 8 + j) * HH + nt * 16 + l15]);
  #pragma unroll
  for (int ks = 0; ks < 2; ks++)
    #pragma unroll
    for (int dt2 = 0; dt2 < 2; dt2++)
      #pragma unroll
      for (int j = 0; j < 8; j++)
        bw3[ks][dt2][j] = (short)f2b_rn(W3f[(ks * 32 + quad * 8 + j) * DD + dt2 * 16 + l15]);

  // ---- G1: wave e -> M-tile e&3, N-tiles {(e>>2)*2, (e>>2)*2+1}; dx-mean folded ----
  const int g1mt = e & 3;
  const int g1n0 = (e >> 2) * 2;
  short8 bg1x[2], bg1f[2];
  #pragma unroll
  for (int ni = 0; ni < 2; ni++)
    #pragma unroll
    for (int j = 0; j < 8; j++) {
      bg1x[ni][j] = (short)f2b_rn(Gw1[(quad * 8 + j) * HH + (g1n0 + ni) * 16 + l15]);
      bg1f[ni][j] = (short)f2b_rn(0.125f * Gw1[(DD + quad * 8 + j) * HH + (g1n0 + ni) * 16 + l15]);
    }
  const float gb1a = Gb1[g1n0 * 16 + l15];
  const float gb1b = Gb1[(g1n0 + 1) * 16 + l15];

  short8 bg2[2];
  float gb2v = 0.f;
  if (e < 4) {                         // G2: waves 0-3, M-tile = e
    #pragma unroll
    for (int ks = 0; ks < 2; ks++)
      #pragma unroll
      for (int j = 0; j < 8; j++)
        bg2[ks][j] = (short)((l15 < 8) ? f2b_rn(Gw2[(ks * 32 + quad * 8 + j) * EE + l15]) : 0);
    gb2v = (l15 < 8) ? Gb2[l15] : 0.f;
  }

  // per-lane C-init components (col-only), bf16-packed
  u32 c1p[4], c2p[2], c3p;
  #pragma unroll
  for (int nt = 0; nt < 4; nt++)
    c1p[nt] = pack2_rn(b1f[nt * 16 + l15], W1f[DD * HH + nt * 16 + l15]);
  #pragma unroll
  for (int p = 0; p < 2; p++)
    c2p[p] = pack2_rn(b2f[(2 * p) * 16 + l15], b2f[(2 * p + 1) * 16 + l15]);
  c3p = pack2_rn(b3f[l15], b3f[16 + l15]);

  // ---- state init: lane owns dims 4e..4e+3 of elem = lane ----
  float xst[4], xacc[4];
  {
    const float4 v = *(const float4*)(x0 + b * DD + 4 * e);
    xst[0] = v.x; xst[1] = v.y; xst[2] = v.z; xst[3] = v.w;
    xacc[0] = v.x; xacc[1] = v.y; xacc[2] = v.z; xacc[3] = v.w;
    u32x2 p; p.x = pack2_rn(v.x, v.y); p.y = pack2_rn(v.z, v.w);
    *(u32x2*)&xdb[lane * 20 + 2 * e] = p;
    *(float4*)(out + b * TT * DD + 4 * e) = v;
  }
  __syncthreads();

  u16* const fw16 = (u16*)fsb;               // f, row stride 264 u16, 16B-block swizzled
  u16* const us16 = (u16*)usb;               // U, row stride 72 u16

  #pragma unroll 1
  for (int step = 0; step < TT - 1; step++) {
    const float t0 = tspan[step];
    const float t1 = tspan[step + 1];
    const float dt = t1 - t0;

    #pragma unroll 1
    for (int s = 0; s < 4; s++) {
      const float tcur = (s == 0) ? t0 : ((s == 3) ? t1 : t0 + 0.5f * dt);

      f32x4 c1i[4];
      #pragma unroll
      for (int nt = 0; nt < 4; nt++)
        c1i[nt] = bcast4(__builtin_fmaf(tcur, unp_hi(c1p[nt]), unp_lo(c1p[nt])));

      // ========== Phase A: expert MLP via MFMA (4 M-tiles, ping-pong scratch) ==========
      #pragma unroll 2
      for (int mt = 0; mt < 4; mt++) {
        u32* const hw   = hs + e * 1152 + (mt & 1) * 576;   // disjoint region per mt parity
        u16* const hw16 = (u16*)hw;

        const short8 a1 = lds_frag(&xdb[(mt * 16 + l15) * 20 + quad * 4]);
        f32x4 h1a[4];
        #pragma unroll
        for (int nt = 0; nt < 4; nt++)
          h1a[nt] = __builtin_amdgcn_mfma_f32_16x16x32_bf16(a1, bw1[nt], c1i[nt], 0, 0, 0);
        #pragma unroll
        for (int nt = 0; nt < 4; nt++)
          #pragma unroll
          for (int r = 0; r < 4; r++)
            hw16[(quad * 4 + r) * 72 + nt * 16 + l15] = f2b_rn(fast_tanh(h1a[nt][r]));

        f32x4 h2a[4];
        #pragma unroll
        for (int nt = 0; nt < 4; nt++)
          h2a[nt] = bcast4((nt & 1) ? unp_hi(c2p[nt >> 1]) : unp_lo(c2p[nt >> 1]));
        #pragma unroll
        for (int ks = 0; ks < 2; ks++) {
          const short8 a2 = lds_frag(&hw[l15 * 36 + ks * 16 + quad * 4]);
          #pragma unroll
          for (int nt = 0; nt < 4; nt++)
            h2a[nt] = __builtin_amdgcn_mfma_f32_16x16x32_bf16(a2, bw2[ks][nt], h2a[nt], 0, 0, 0);
        }
        #pragma unroll
        for (int nt = 0; nt < 4; nt++)
          #pragma unroll
          for (int r = 0; r < 4; r++)
            hw16[(quad * 4 + r) * 72 + nt * 16 + l15] = f2b_rn(fast_tanh(h2a[nt][r]));

        f32x4 fa[2];
        #pragma unroll
        for (int dt2 = 0; dt2 < 2; dt2++)
          fa[dt2] = bcast4(dt2 ? unp_hi(c3p) : unp_lo(c3p));
        #pragma unroll
        for (int ks = 0; ks < 2; ks++) {
          const short8 a3 = lds_frag(&hw[l15 * 36 + ks * 16 + quad * 4]);
          #pragma unroll
          for (int dt2 = 0; dt2 < 2; dt2++)
            fa[dt2] = __builtin_amdgcn_mfma_f32_16x16x32_bf16(a3, bw3[ks][dt2], fa[dt2], 0, 0, 0);
        }
        // f write, 16B-block XOR swizzle: block = c16>>3, block' = block ^ (m&7)
        #pragma unroll
        for (int dt2 = 0; dt2 < 2; dt2++)
          #pragma unroll
          for (int r = 0; r < 4; r++) {
            const int m = mt * 16 + quad * 4 + r;
            const int c16 = e * 32 + dt2 * 16 + l15;
            fw16[m * 264 + ((((c16 >> 3) ^ (m & 7)) << 3) | (c16 & 7))] = f2b_rn(fa[dt2][r]);
          }
      } // mt
      __syncthreads();   // fs complete

      // ========== G1: U = tanh(x@Gw1x + (Σ_e f_e)@(Gw1dx/8) + Gb1), 2 N-tiles/wave ==========
      {
        f32x4 u0 = bcast4(gb1a), u1 = bcast4(gb1b);
        const int mg = g1mt * 16 + l15;
        const short8 ax = lds_frag(&xdb[mg * 20 + quad * 4]);
        u0 = __builtin_amdgcn_mfma_f32_16x16x32_bf16(ax, bg1x[0], u0, 0, 0, 0);
        u1 = __builtin_amdgcn_mfma_f32_16x16x32_bf16(ax, bg1x[1], u1, 0, 0, 0);
        #pragma unroll
        for (int kb = 0; kb < 8; kb++) {
          // u32 block = kb*4+quad, swizzled by row mg
          const short8 af = lds_frag(&fsb[mg * 132 + (((kb * 4 + quad) ^ (mg & 7)) << 2)]);
          u0 = __builtin_amdgcn_mfma_f32_16x16x32_bf16(af, bg1f[0], u0, 0, 0, 0);
          u1 = __builtin_amdgcn_mfma_f32_16x16x32_bf16(af, bg1f[1], u1, 0, 0, 0);
        }
        #pragma unroll
        for (int r = 0; r < 4; r++) {
          us16[(g1mt * 16 + quad * 4 + r) * 72 + g1n0 * 16 + l15]       = f2b_rn(fast_tanh(u0[r]));
          us16[(g1mt * 16 + quad * 4 + r) * 72 + (g1n0 + 1) * 16 + l15] = f2b_rn(fast_tanh(u1[r]));
        }
      }
      __syncthreads();   // U complete

      // ========== G2: logits = U @ Gw2 + Gb2 (waves 0-3, M-tile = e) ==========
      if (e < 4) {
        f32x4 lv = bcast4(gb2v);
        #pragma unroll
        for (int ks = 0; ks < 2; ks++) {
          const short8 ag = lds_frag(&usb[(e * 16 + l15) * 36 + ks * 16 + quad * 4]);
          lv = __builtin_amdgcn_mfma_f32_16x16x32_bf16(ag, bg2[ks], lv, 0, 0, 0);
        }
        if (l15 < 8) {
          #pragma unroll
          for (int r = 0; r < 4; r++)
            lg[(e * 16 + quad * 4 + r) * 12 + l15] = lv[r];
        }
      }
      __syncthreads();   // logits complete

      // ========== C: softmax (no max-sub; logits bounded) + weighted sum + RK4 ==========
      {
        const float4 la0 = *(const float4*)&lg[lane * 12 + 0];
        const float4 la1 = *(const float4*)&lg[lane * 12 + 4];
        float w8[EE];
        w8[0] = __expf(la0.x); w8[1] = __expf(la0.y);
        w8[2] = __expf(la0.z); w8[3] = __expf(la0.w);
        w8[4] = __expf(la1.x); w8[5] = __expf(la1.y);
        w8[6] = __expf(la1.z); w8[7] = __expf(la1.w);
        float ss = 0.f;
        #pragma unroll
        for (int j = 0; j < EE; j++) ss += w8[j];
        const float inv = __builtin_amdgcn_rcpf(ss);

        float kc[4] = {0.f, 0.f, 0.f, 0.f};
        #pragma unroll
        for (int j = 0; j < EE; j++) {
          const float wg = w8[j] * inv;
          // u32 cols {j*16+2e, j*16+2e+1}: block = j*4+(e>>1) (swizzled by row=lane), within = 2e&3
          const u32x2 p = *(const u32x2*)&fsb[lane * 132 +
              ((((j * 4 + (e >> 1)) ^ (lane & 7)) << 2) | ((2 * e) & 3))];
          kc[0] = __builtin_fmaf(wg, unp_lo(p.x), kc[0]);
          kc[1] = __builtin_fmaf(wg, unp_hi(p.x), kc[1]);
          kc[2] = __builtin_fmaf(wg, unp_lo(p.y), kc[2]);
          kc[3] = __builtin_fmaf(wg, unp_hi(p.y), kc[3]);
        }

        const float wk = (s == 1 || s == 2) ? 2.f : 1.f;
        const float ak = dt * (1.f / 6.f) * wk;
        #pragma unroll
        for (int q = 0; q < 4; q++) xacc[q] = __builtin_fmaf(ak, kc[q], xacc[q]);

        float xn[4];
        if (s < 3) {
          const float cn = (s == 2) ? dt : 0.5f * dt;
          #pragma unroll
          for (int q = 0; q < 4; q++) xn[q] = __builtin_fmaf(cn, kc[q], xst[q]);
        } else {
          #pragma unroll
          for (int q = 0; q < 4; q++) { xst[q] = xacc[q]; xn[q] = xacc[q]; }
          float4 o; o.x = xn[0]; o.y = xn[1]; o.z = xn[2]; o.w = xn[3];
          *(float4*)(out + (b * TT + step + 1) * DD + 4 * e) = o;
        }
        u32x2 p; p.x = pack2_rn(xn[0], xn[1]); p.y = pack2_rn(xn[2], xn[3]);
        *(u32x2*)&xdb[lane * 20 + 2 * e] = p;
      }
      __syncthreads();   // end of stage
    } // stages
  } // steps
}

extern "C" void kernel_launch(void* const* d_in, const int* in_sizes, int n_in,
                              void* d_out, int out_size, void* d_ws, size_t ws_size,
                              hipStream_t stream)
{
  const float* x0    = (const float*)d_in[0];
  const float* tspan = (const float*)d_in[1];
  const float* W1  = (const float*)d_in[2];
  const float* b1  = (const float*)d_in[3];
  const float* W2  = (const float*)d_in[4];
  const float* b2  = (const float*)d_in[5];
  const float* W3  = (const float*)d_in[6];
  const float* b3  = (const float*)d_in[7];
  const float* Gw1 = (const float*)d_in[8];
  const float* Gb1 = (const float*)d_in[9];
  const float* Gw2 = (const float*)d_in[10];
  const float* Gb2 = (const float*)d_in[11];

  // Opt in to >64 KB dynamic LDS (160 KB/CU on gfx950). Host-side, idempotent,
  // graph-capture safe. Called unconditionally every launch.
  (void)hipFuncSetAttribute((const void*)ame_ode_kernel,
                            hipFuncAttributeMaxDynamicSharedMemorySize, DYN_LDS);

  ame_ode_kernel<<<BATCH / EPB, 512, DYN_LDS, stream>>>(
      x0, tspan, W1, b1, W2, b2, W3, b3, Gw1, Gb1, Gw2, Gb2, (float*)d_out);
}

// Round 14
// 319.074 us; speedup vs baseline: 1.1038x; 1.1038x over previous
//
#include <hip/hip_runtime.h>
#include <hip/hip_bf16.h>

typedef unsigned int u32;
typedef unsigned short u16;
typedef __attribute__((ext_vector_type(8))) short short8;   // 8 bf16 (4 VGPRs) MFMA A/B frag
typedef __attribute__((ext_vector_type(4))) float f32x4;    // MFMA C/D frag
typedef __attribute__((ext_vector_type(4))) u32 u32x4;
typedef __attribute__((ext_vector_type(2))) u32 u32x2;

#define DD 32
#define EE 8
#define HH 64
#define TT 10
#define BATCH 16384
#define EPB 64          // batch elements per block (grid 256 = 1 block/CU)
#define DYN_LDS 88064   // bytes: xdb 5120 + fsb 33792 + lg 3072 + usb 9216 + scratch 36864

#if __has_builtin(__builtin_amdgcn_exp2f)
#define EXP2F(x) __builtin_amdgcn_exp2f(x)
#else
#define EXP2F(x) __builtin_exp2f(x)
#endif

__device__ __forceinline__ float fast_tanh(float x) {
  float e = EXP2F(x * 2.885390082f);
  return 1.f - 2.f * __builtin_amdgcn_rcpf(e + 1.f);
}
__device__ __forceinline__ u16 f2b_rn(float v) {
  return (u16)((__float_as_uint(v) + 0x8000u) >> 16);
}
__device__ __forceinline__ u32 pack2_rn(float a, float b) {
  return __builtin_amdgcn_perm(__float_as_uint(b) + 0x8000u,
                               __float_as_uint(a) + 0x8000u, 0x07060302u);
}
__device__ __forceinline__ float unp_lo(u32 p) { return __uint_as_float(p << 16); }
__device__ __forceinline__ float unp_hi(u32 p) { return __uint_as_float(p & 0xffff0000u); }
__device__ __forceinline__ short8 lds_frag(const u32* p) {
  u32x4 v = *(const u32x4*)p;               // ds_read_b128 (16B-aligned by construction)
  return __builtin_bit_cast(short8, v);
}
__device__ __forceinline__ f32x4 bcast4(float v) { f32x4 c; c[0]=v; c[1]=v; c[2]=v; c[3]=v; return c; }

// wave = expert (8 waves, 512 thr), 64 elems/block, grid 256.
// == R12 structure (best: 276 us steady), plus no-max-sub softmax (validated
// bit-identical in R8 and R13). R13's fsb XOR-swizzle is REVERTED: it raised
// SQ_LDS_BANK_CONFLICT 1.15e7 -> 2.92e7 (the phase-A u16 scatter writes
// dominate DS traffic and the swizzle folded cross-quad writes onto shared
// banks) and cost 11%. Plain stride-132 rows are the measured optimum.
// Ping-pong per-wave h-scratch (mt parity) lets consecutive M-tiles overlap;
// total LDS 88 KB -> dynamic LDS opt-in (160 KB/CU, still 1 block/CU).
// REGISTER LAW (R5-R13): waves/SIMD = floor(256/VGPR). Weights-resident needs
// VGPR in [100,128] -> 2 waves/SIMD, structural. Any launch-bounds cap <=128
// dumps the 64-VGPR weight frags (FETCH 2 MB -> GBs, 2.5-5x slower) — plain
// __launch_bounds__(512) only. Kernel is co-limited: VALU ~64%, DS ~64%,
// MFMA ~15%, 4 barriers/stage at 2 waves/SIMD.
__global__ __launch_bounds__(512) void ame_ode_kernel(
    const float* __restrict__ x0, const float* __restrict__ tspan,
    const float* __restrict__ W1, const float* __restrict__ b1,
    const float* __restrict__ W2, const float* __restrict__ b2,
    const float* __restrict__ W3, const float* __restrict__ b3,
    const float* __restrict__ Gw1, const float* __restrict__ Gb1,
    const float* __restrict__ Gw2, const float* __restrict__ Gb2,
    float* __restrict__ out)
{
  extern __shared__ __align__(16) u32 dynbuf[];
  u32*  const xdb = dynbuf;                    // [EPB][20] u32: xs bf16x2 (5120 B)
  u32*  const fsb = dynbuf + 1280;             // [EPB][132] u32: f bf16x2, 16B-aligned rows (33792 B)
  float* const lg = (float*)(dynbuf + 9728);   // [EPB][12]: logits (3072 B)
  u32*  const usb = dynbuf + 10496;            // [EPB][36] u32: gating U (9216 B)
  u32*  const hs  = dynbuf + 12800;            // [8 waves][2 regions][16][36] u32 scratch (36864 B)

  const int tid  = threadIdx.x;
  const int lane = tid & 63;
  const int l15  = lane & 15;
  const int quad = lane >> 4;
  const int e    = __builtin_amdgcn_readfirstlane(tid >> 6);   // wave-uniform expert id
  const int b    = blockIdx.x * EPB + lane;                    // this lane's batch element

  const float* W1f = W1 + e * (DD + 1) * HH;
  const float* b1f = b1 + e * HH;
  const float* W2f = W2 + e * HH * HH;
  const float* b2f = b2 + e * HH;
  const float* W3f = W3 + e * HH * DD;
  const float* b3f = b3 + e * DD;

  // ---- expert-weight B-frags: B[k=quad*8+j][n=l15(+16nt)] ----
  short8 bw1[4], bw2[2][4], bw3[2][2];
  #pragma unroll
  for (int nt = 0; nt < 4; nt++)
    #pragma unroll
    for (int j = 0; j < 8; j++)
      bw1[nt][j] = (short)f2b_rn(W1f[(quad * 8 + j) * HH + nt * 16 + l15]);
  #pragma unroll
  for (int ks = 0; ks < 2; ks++)
    #pragma unroll
    for (int nt = 0; nt < 4; nt++)
      #pragma unroll
      for (int j = 0; j < 8; j++)
        bw2[ks][nt][j] = (short)f2b_rn(W2f[(ks * 32 + quad * 8 + j) * HH + nt * 16 + l15]);
  #pragma unroll
  for (int ks = 0; ks < 2; ks++)
    #pragma unroll
    for (int dt2 = 0; dt2 < 2; dt2++)
      #pragma unroll
      for (int j = 0; j < 8; j++)
        bw3[ks][dt2][j] = (short)f2b_rn(W3f[(ks * 32 + quad * 8 + j) * DD + dt2 * 16 + l15]);

  // ---- G1: wave e -> M-tile e&3, N-tiles {(e>>2)*2, (e>>2)*2+1}; dx-mean folded ----
  const int g1mt = e & 3;
  const int g1n0 = (e >> 2) * 2;
  short8 bg1x[2], bg1f[2];
  #pragma unroll
  for (int ni = 0; ni < 2; ni++)
    #pragma unroll
    for (int j = 0; j < 8; j++) {
      bg1x[ni][j] = (short)f2b_rn(Gw1[(quad * 8 + j) * HH + (g1n0 + ni) * 16 + l15]);
      bg1f[ni][j] = (short)f2b_rn(0.125f * Gw1[(DD + quad * 8 + j) * HH + (g1n0 + ni) * 16 + l15]);
    }
  const float gb1a = Gb1[g1n0 * 16 + l15];
  const float gb1b = Gb1[(g1n0 + 1) * 16 + l15];

  short8 bg2[2];
  float gb2v = 0.f;
  if (e < 4) {                         // G2: waves 0-3, M-tile = e
    #pragma unroll
    for (int ks = 0; ks < 2; ks++)
      #pragma unroll
      for (int j = 0; j < 8; j++)
        bg2[ks][j] = (short)((l15 < 8) ? f2b_rn(Gw2[(ks * 32 + quad * 8 + j) * EE + l15]) : 0);
    gb2v = (l15 < 8) ? Gb2[l15] : 0.f;
  }

  // per-lane C-init components (col-only), bf16-packed
  u32 c1p[4], c2p[2], c3p;
  #pragma unroll
  for (int nt = 0; nt < 4; nt++)
    c1p[nt] = pack2_rn(b1f[nt * 16 + l15], W1f[DD * HH + nt * 16 + l15]);
  #pragma unroll
  for (int p = 0; p < 2; p++)
    c2p[p] = pack2_rn(b2f[(2 * p) * 16 + l15], b2f[(2 * p + 1) * 16 + l15]);
  c3p = pack2_rn(b3f[l15], b3f[16 + l15]);

  // ---- state init: lane owns dims 4e..4e+3 of elem = lane ----
  float xst[4], xacc[4];
  {
    const float4 v = *(const float4*)(x0 + b * DD + 4 * e);
    xst[0] = v.x; xst[1] = v.y; xst[2] = v.z; xst[3] = v.w;
    xacc[0] = v.x; xacc[1] = v.y; xacc[2] = v.z; xacc[3] = v.w;
    u32x2 p; p.x = pack2_rn(v.x, v.y); p.y = pack2_rn(v.z, v.w);
    *(u32x2*)&xdb[lane * 20 + 2 * e] = p;
    *(float4*)(out + b * TT * DD + 4 * e) = v;
  }
  __syncthreads();

  u16* const fw16 = (u16*)fsb;               // f, row stride 264 u16
  u16* const us16 = (u16*)usb;               // U, row stride 72 u16

  #pragma unroll 1
  for (int step = 0; step < TT - 1; step++) {
    const float t0 = tspan[step];
    const float t1 = tspan[step + 1];
    const float dt = t1 - t0;

    #pragma unroll 1
    for (int s = 0; s < 4; s++) {
      const float tcur = (s == 0) ? t0 : ((s == 3) ? t1 : t0 + 0.5f * dt);

      f32x4 c1i[4];
      #pragma unroll
      for (int nt = 0; nt < 4; nt++)
        c1i[nt] = bcast4(__builtin_fmaf(tcur, unp_hi(c1p[nt]), unp_lo(c1p[nt])));

      // ========== Phase A: expert MLP via MFMA (4 M-tiles, ping-pong scratch) ==========
      #pragma unroll 2
      for (int mt = 0; mt < 4; mt++) {
        u32* const hw   = hs + e * 1152 + (mt & 1) * 576;   // disjoint region per mt parity
        u16* const hw16 = (u16*)hw;

        const short8 a1 = lds_frag(&xdb[(mt * 16 + l15) * 20 + quad * 4]);
        f32x4 h1a[4];
        #pragma unroll
        for (int nt = 0; nt < 4; nt++)
          h1a[nt] = __builtin_amdgcn_mfma_f32_16x16x32_bf16(a1, bw1[nt], c1i[nt], 0, 0, 0);
        #pragma unroll
        for (int nt = 0; nt < 4; nt++)
          #pragma unroll
          for (int r = 0; r < 4; r++)
            hw16[(quad * 4 + r) * 72 + nt * 16 + l15] = f2b_rn(fast_tanh(h1a[nt][r]));

        f32x4 h2a[4];
        #pragma unroll
        for (int nt = 0; nt < 4; nt++)
          h2a[nt] = bcast4((nt & 1) ? unp_hi(c2p[nt >> 1]) : unp_lo(c2p[nt >> 1]));
        #pragma unroll
        for (int ks = 0; ks < 2; ks++) {
          const short8 a2 = lds_frag(&hw[l15 * 36 + ks * 16 + quad * 4]);
          #pragma unroll
          for (int nt = 0; nt < 4; nt++)
            h2a[nt] = __builtin_amdgcn_mfma_f32_16x16x32_bf16(a2, bw2[ks][nt], h2a[nt], 0, 0, 0);
        }
        #pragma unroll
        for (int nt = 0; nt < 4; nt++)
          #pragma unroll
          for (int r = 0; r < 4; r++)
            hw16[(quad * 4 + r) * 72 + nt * 16 + l15] = f2b_rn(fast_tanh(h2a[nt][r]));

        f32x4 fa[2];
        #pragma unroll
        for (int dt2 = 0; dt2 < 2; dt2++)
          fa[dt2] = bcast4(dt2 ? unp_hi(c3p) : unp_lo(c3p));
        #pragma unroll
        for (int ks = 0; ks < 2; ks++) {
          const short8 a3 = lds_frag(&hw[l15 * 36 + ks * 16 + quad * 4]);
          #pragma unroll
          for (int dt2 = 0; dt2 < 2; dt2++)
            fa[dt2] = __builtin_amdgcn_mfma_f32_16x16x32_bf16(a3, bw3[ks][dt2], fa[dt2], 0, 0, 0);
        }
        #pragma unroll
        for (int dt2 = 0; dt2 < 2; dt2++)
          #pragma unroll
          for (int r = 0; r < 4; r++)
            fw16[(mt * 16 + quad * 4 + r) * 264 + e * 32 + dt2 * 16 + l15] = f2b_rn(fa[dt2][r]);
      } // mt
      __syncthreads();   // fs complete

      // ========== G1: U = tanh(x@Gw1x + (Σ_e f_e)@(Gw1dx/8) + Gb1), 2 N-tiles/wave ==========
      {
        f32x4 u0 = bcast4(gb1a), u1 = bcast4(gb1b);
        const int mg = g1mt * 16 + l15;
        const short8 ax = lds_frag(&xdb[mg * 20 + quad * 4]);
        u0 = __builtin_amdgcn_mfma_f32_16x16x32_bf16(ax, bg1x[0], u0, 0, 0, 0);
        u1 = __builtin_amdgcn_mfma_f32_16x16x32_bf16(ax, bg1x[1], u1, 0, 0, 0);
        #pragma unroll
        for (int kb = 0; kb < 8; kb++) {
          const short8 af = lds_frag(&fsb[mg * 132 + kb * 16 + quad * 4]);
          u0 = __builtin_amdgcn_mfma_f32_16x16x32_bf16(af, bg1f[0], u0, 0, 0, 0);
          u1 = __builtin_amdgcn_mfma_f32_16x16x32_bf16(af, bg1f[1], u1, 0, 0, 0);
        }
        #pragma unroll
        for (int r = 0; r < 4; r++) {
          us16[(g1mt * 16 + quad * 4 + r) * 72 + g1n0 * 16 + l15]       = f2b_rn(fast_tanh(u0[r]));
          us16[(g1mt * 16 + quad * 4 + r) * 72 + (g1n0 + 1) * 16 + l15] = f2b_rn(fast_tanh(u1[r]));
        }
      }
      __syncthreads();   // U complete

      // ========== G2: logits = U @ Gw2 + Gb2 (waves 0-3, M-tile = e) ==========
      if (e < 4) {
        f32x4 lv = bcast4(gb2v);
        #pragma unroll
        for (int ks = 0; ks < 2; ks++) {
          const short8 ag = lds_frag(&usb[(e * 16 + l15) * 36 + ks * 16 + quad * 4]);
          lv = __builtin_amdgcn_mfma_f32_16x16x32_bf16(ag, bg2[ks], lv, 0, 0, 0);
        }
        if (l15 < 8) {
          #pragma unroll
          for (int r = 0; r < 4; r++)
            lg[(e * 16 + quad * 4 + r) * 12 + l15] = lv[r];
        }
      }
      __syncthreads();   // logits complete

      // ========== C: softmax (no max-sub; logits bounded) + weighted sum + RK4 ==========
      {
        const float4 la0 = *(const float4*)&lg[lane * 12 + 0];
        const float4 la1 = *(const float4*)&lg[lane * 12 + 4];
        float w8[EE];
        w8[0] = __expf(la0.x); w8[1] = __expf(la0.y);
        w8[2] = __expf(la0.z); w8[3] = __expf(la0.w);
        w8[4] = __expf(la1.x); w8[5] = __expf(la1.y);
        w8[6] = __expf(la1.z); w8[7] = __expf(la1.w);
        float ss = 0.f;
        #pragma unroll
        for (int j = 0; j < EE; j++) ss += w8[j];
        const float inv = __builtin_amdgcn_rcpf(ss);

        float kc[4] = {0.f, 0.f, 0.f, 0.f};
        #pragma unroll
        for (int j = 0; j < EE; j++) {
          const float wg = w8[j] * inv;
          const u32x2 p = *(const u32x2*)&fsb[lane * 132 + j * 16 + 2 * e];
          kc[0] = __builtin_fmaf(wg, unp_lo(p.x), kc[0]);
          kc[1] = __builtin_fmaf(wg, unp_hi(p.x), kc[1]);
          kc[2] = __builtin_fmaf(wg, unp_lo(p.y), kc[2]);
          kc[3] = __builtin_fmaf(wg, unp_hi(p.y), kc[3]);
        }

        const float wk = (s == 1 || s == 2) ? 2.f : 1.f;
        const float ak = dt * (1.f / 6.f) * wk;
        #pragma unroll
        for (int q = 0; q < 4; q++) xacc[q] = __builtin_fmaf(ak, kc[q], xacc[q]);

        float xn[4];
        if (s < 3) {
          const float cn = (s == 2) ? dt : 0.5f * dt;
          #pragma unroll
          for (int q = 0; q < 4; q++) xn[q] = __builtin_fmaf(cn, kc[q], xst[q]);
        } else {
          #pragma unroll
          for (int q = 0; q < 4; q++) { xst[q] = xacc[q]; xn[q] = xacc[q]; }
          float4 o; o.x = xn[0]; o.y = xn[1]; o.z = xn[2]; o.w = xn[3];
          *(float4*)(out + (b * TT + step + 1) * DD + 4 * e) = o;
        }
        u32x2 p; p.x = pack2_rn(xn[0], xn[1]); p.y = pack2_rn(xn[2], xn[3]);
        *(u32x2*)&xdb[lane * 20 + 2 * e] = p;
      }
      __syncthreads();   // end of stage
    } // stages
  } // steps
}

extern "C" void kernel_launch(void* const* d_in, const int* in_sizes, int n_in,
                              void* d_out, int out_size, void* d_ws, size_t ws_size,
                              hipStream_t stream)
{
  const float* x0    = (const float*)d_in[0];
  const float* tspan = (const float*)d_in[1];
  const float* W1  = (const float*)d_in[2];
  const float* b1  = (const float*)d_in[3];
  const float* W2  = (const float*)d_in[4];
  const float* b2  = (const float*)d_in[5];
  const float* W3  = (const float*)d_in[6];
  const float* b3  = (const float*)d_in[7];
  const float* Gw1 = (const float*)d_in[8];
  const float* Gb1 = (const float*)d_in[9];
  const float* Gw2 = (const float*)d_in[10];
  const float* Gb2 = (const float*)d_in[11];

  // Opt in to >64 KB dynamic LDS (160 KB/CU on gfx950). Host-side, idempotent,
  // graph-capture safe. Called unconditionally every launch.
  (void)hipFuncSetAttribute((const void*)ame_ode_kernel,
                            hipFuncAttributeMaxDynamicSharedMemorySize, DYN_LDS);

  ame_ode_kernel<<<BATCH / EPB, 512, DYN_LDS, stream>>>(
      x0, tspan, W1, b1, W2, b2, W3, b3, Gw1, Gb1, Gw2, Gb2, (float*)d_out);
}